// Round 8
// baseline (49.859 us; speedup 1.0000x reference)
//
#include <hip/hip_runtime.h>

// SSF_Extractor: out = x * resize_bilinear_ac(local_unbiased_var_5x5(x), 256, 256)
// x: (8, 64, 256, 256) fp32.
//
// Deep-pipelined single-load streaming: one 64-lane wave owns one
// 32-output-row full-width strip; lane l owns columns 4l..4l+3. A 7-deep
// named-register ring (R0..R5, xn) holds the last 7 x-rows (each byte loaded
// from global exactly once per wave). Iteration u:
//   - prefetch x row y0+u+1 (clamped);
//   - var row a = y0-4+u from fresh 5-row sums of R2..R5,xn; neighbor
//     column-sums via __shfl; write to depth-8 LDS ring;
//   - EMIT row gy = y0+u-6 from R0 using gather registers gl/gh prepared one
//     iteration earlier (vy1(gy) <= a-1, so the gather never depends on this
//     iteration's ring write);
//   - PREPARE next emit's gather (ring reads have a full iteration of slack
//     before first use -> DS latency off the critical path).

namespace {

constexpr int W = 256;
constexpr int STRIP = 32;
#define SC (251.0f / 255.0f)  // align_corners scale (h-1)/(H-1)

__device__ __forceinline__ float4 ldrow(const float* xi, int r, int lo, int hi,
                                        int c0) {
  r = r < lo ? lo : (r > hi ? hi : r);
  return *(const float4*)(xi + (size_t)r * W + c0);
}

__global__ __launch_bounds__(256, 4) void ssf_pipe(const float* __restrict__ x,
                                                   float* __restrict__ out) {
  __shared__ float ring_all[4][8 * 256];  // depth-8 var ring per wave (8 KB)

  const int tid = threadIdx.x;
  const int lane = tid & 63;
  const int wv = tid >> 6;
  float* const ring = ring_all[wv];

  // XCD-chunked block swizzle (1024 blocks, 8 XCDs -> bijective).
  const int b = blockIdx.x;
  const int bs = (b & 7) * 128 + (b >> 3);
  const int sid = __builtin_amdgcn_readfirstlane(bs * 4 + wv);
  const int img = sid >> 3;                // 0..511
  const int y0 = (sid & 7) * STRIP;        // strip base output row

  const float* const xi = x + (size_t)img * (W * W);
  float* const oi = out + (size_t)img * (W * W);

  const int vymin = (y0 * 251) / 255;
  int vymax = ((y0 + STRIP - 1) * 251) / 255 + 1;
  if (vymax > 251) vymax = 251;
  const int hi = vymax + 4;  // last x row used (<= 255)

  const int c0 = lane * 4;

  // ---- Per-lane horizontal bilinear constants ----
  const int q0 = (int)floorf((float)c0 * SC);
  float wxv[4];
  bool selA[4], selB[4];
#pragma unroll
  for (int i = 0; i < 4; ++i) {
    float xs = (float)(c0 + i) * SC;
    float x0f = floorf(xs);
    int x0i = (int)x0f;
    wxv[i] = xs - x0f;
    selA[i] = (x0i - q0) == i;
    int x1i = x0i + 1;
    if (x1i > 251) x1i = 251;
    selB[i] = (x1i - q0) == (i + 1);
  }

  // ---- Preload register ring: rows y0-6..y0 (clamped to [vymin, hi]) ----
  // Invariant at start of iter u: Rk = row y0-6+k+u (clamped), xn = row y0+u.
  float4 R0 = ldrow(xi, y0 - 6, vymin, hi, c0);
  float4 R1 = ldrow(xi, y0 - 5, vymin, hi, c0);
  float4 R2 = ldrow(xi, y0 - 4, vymin, hi, c0);
  float4 R3 = ldrow(xi, y0 - 3, vymin, hi, c0);
  float4 R4 = ldrow(xi, y0 - 2, vymin, hi, c0);
  float4 R5 = ldrow(xi, y0 - 1, vymin, hi, c0);
  float4 xn = ldrow(xi, y0, vymin, hi, c0);

  const int nsrc = (lane < 63) ? lane + 1 : 63;  // neighbor lane (63: junk)

  int cur = -1000;
  float gl[5] = {0.f, 0.f, 0.f, 0.f, 0.f};  // gather: ring row vy  @ q0..q0+4
  float gh[5] = {0.f, 0.f, 0.f, 0.f, 0.f};  // gather: ring row vy1 @ q0..q0+4

  for (int u = 0; u <= 37; ++u) {  // fixed 38 iterations
    // ---- Prefetch next x row (clamped; tail duplicates are L1-hot) ----
    float4 xnn = ldrow(xi, y0 + u + 1, vymin, hi, c0);

    // ---- Var row a = y0-4+u (wave-uniform guard) ----
    const int a = y0 - 4 + u;
    if (a >= vymin && a <= vymax) {
      float r1[4] = {R2.x, R2.y, R2.z, R2.w};
      float r2[4] = {R3.x, R3.y, R3.z, R3.w};
      float r3[4] = {R4.x, R4.y, R4.z, R4.w};
      float r4[4] = {R5.x, R5.y, R5.z, R5.w};
      float r5[4] = {xn.x, xn.y, xn.z, xn.w};
      float s5[4], q5[4];
#pragma unroll
      for (int i = 0; i < 4; ++i) {
        s5[i] = ((r1[i] + r2[i]) + (r3[i] + r4[i])) + r5[i];
        q5[i] = fmaf(r1[i], r1[i],
                     fmaf(r2[i], r2[i],
                          fmaf(r3[i], r3[i], fmaf(r4[i], r4[i], r5[i] * r5[i]))));
      }
      // Neighbor exchange: next lane's 4 column sums (bpermute).
      float ns0 = __shfl(s5[0], nsrc, 64), ns1 = __shfl(s5[1], nsrc, 64);
      float ns2 = __shfl(s5[2], nsrc, 64), ns3 = __shfl(s5[3], nsrc, 64);
      float nq0 = __shfl(q5[0], nsrc, 64), nq1 = __shfl(q5[1], nsrc, 64);
      float nq2 = __shfl(q5[2], nsrc, 64), nq3 = __shfl(q5[3], nsrc, 64);
      // Horizontal 5-tap (sliding) + unbiased variance, var cols c0..c0+3.
      float hs0 = ((s5[0] + s5[1]) + (s5[2] + s5[3])) + ns0;
      float hq0 = ((q5[0] + q5[1]) + (q5[2] + q5[3])) + nq0;
      float hs1 = hs0 - s5[0] + ns1;
      float hq1 = hq0 - q5[0] + nq1;
      float hs2 = hs1 - s5[1] + ns2;
      float hq2 = hq1 - q5[1] + nq2;
      float hs3 = hs2 - s5[2] + ns3;
      float hq3 = hq2 - q5[2] + nq3;
      float4 vr4;
      vr4.x = (hq0 - hs0 * hs0 * (1.0f / 25.0f)) * (1.0f / 24.0f);
      vr4.y = (hq1 - hs1 * hs1 * (1.0f / 25.0f)) * (1.0f / 24.0f);
      vr4.z = (hq2 - hs2 * hs2 * (1.0f / 25.0f)) * (1.0f / 24.0f);
      vr4.w = (hq3 - hs3 * hs3 * (1.0f / 25.0f)) * (1.0f / 24.0f);
      *(float4*)(ring + (a & 7) * 256 + c0) = vr4;
    }

    // ---- Emit row gy = y0+u-6 from R0, gather prepared last iteration ----
    if (u >= 6) {
      const int gy = y0 + u - 6;
      const int vy = (gy * 251) / 255;  // exact integer floor (wave-uniform)
      float ys = (float)gy * SC;
      float wy = ys - (float)vy;
      float xa[4] = {R0.x, R0.y, R0.z, R0.w};
      float omwy = 1.0f - wy;
      float res[4];
#pragma unroll
      for (int i = 0; i < 4; ++i) {
        float a00 = (i == 0) ? gl[0] : (selA[i] ? gl[i] : gl[i - 1]);
        float a10 = (i == 0) ? gh[0] : (selA[i] ? gh[i] : gh[i - 1]);
        float a01 = selB[i] ? gl[i + 1] : gl[i];
        float a11 = selB[i] ? gh[i + 1] : gh[i];
        // Reference order: rows (wy) first, then cols (wx).
        float left = a00 * omwy + a10 * wy;
        float right = a01 * omwy + a11 * wy;
        res[i] = (left * (1.0f - wxv[i]) + right * wxv[i]) * xa[i];
      }
      *(float4*)(oi + (size_t)gy * W + c0) =
          make_float4(res[0], res[1], res[2], res[3]);
    }

    // ---- Prepare gather for next emit (gy' = y0+u-5); rows <= a are ready --
    if (u >= 5 && u <= 36) {
      const int gyp = y0 + u - 5;
      const int vyp = (gyp * 251) / 255;
      int vy1p = vyp + 1;
      if (vy1p > 251) vy1p = 251;
      if (vyp != cur) {  // wave-uniform
        if (vyp == cur + 1) {
#pragma unroll
          for (int i = 0; i < 5; ++i) gl[i] = gh[i];  // row-carry reuse
        } else {
          const float* rp = ring + (vyp & 7) * 256 + q0;  // first emit only
#pragma unroll
          for (int i = 0; i < 5; ++i) gl[i] = rp[i];
        }
        if (vy1p == vyp) {
#pragma unroll
          for (int i = 0; i < 5; ++i) gh[i] = gl[i];  // bottom clamp
        } else {
          const float* rp = ring + (vy1p & 7) * 256 + q0;
#pragma unroll
          for (int i = 0; i < 5; ++i) gh[i] = rp[i];
        }
        cur = vyp;
      }
    }

    // ---- Static ring shift (named registers, no dynamic indexing) ----
    R0 = R1; R1 = R2; R2 = R3; R3 = R4; R4 = R5; R5 = xn; xn = xnn;
  }
}

}  // namespace

extern "C" void kernel_launch(void* const* d_in, const int* in_sizes, int n_in,
                              void* d_out, int out_size, void* d_ws, size_t ws_size,
                              hipStream_t stream) {
  const float* x = (const float*)d_in[0];
  float* out = (float*)d_out;
  // 4096 strips (512 images x 8 strips), 4 waves (strips) per 256-thread block.
  ssf_pipe<<<dim3(1024), dim3(256), 0, stream>>>(x, out);
}

// Round 10
// 49.399 us; speedup vs baseline: 1.0093x; 1.0093x over previous
//
#include <hip/hip_runtime.h>

// SSF_Extractor: out = x * resize_bilinear_ac(local_unbiased_var_5x5(x), 256, 256)
// x: (8, 64, 256, 256) fp32.
//
// Fully-pipelined single-load streaming: one 64-lane wave owns one
// 32-output-row full-width strip; lane l owns columns 4l..4l+3. A 10-deep
// named-register ring (R0..R5, xn, P1..P3) holds the last 10 x-rows; each x
// byte is loaded from global exactly once per wave, with 3 iterations of
// prefetch slack (~1000 cyc) to cover L3/HBM latency. The neighbor
// column-sum exchange (8 x __shfl) for var row a+1 is ISSUED at iteration u
// and CONSUMED at iteration u+1 -> DS latency off the critical path.
// ORDER MATTERS (r9 bug): emit MUST consume gl/gh before gather-prep
// overwrites them for the next row.
// Iteration u:
//   - issue load of x row y0+u+4 (clamped);
//   - var row a = y0-4+u: pure-VALU finish from last iter's sums/shfl
//     results, write to depth-8 LDS ring;
//   - compute next var row's own column sums + issue its 8 shfls;
//   - EMIT row gy = y0+u-6 from R0 with gather regs prepared last iter;
//   - gather-prep for next emit (ds_reads get ~1 iter of slack).

namespace {

constexpr int W = 256;
constexpr int STRIP = 32;
#define SC (251.0f / 255.0f)  // align_corners scale (h-1)/(H-1)

__device__ __forceinline__ float4 ldrow(const float* xi, int r, int lo, int hi,
                                        int c0) {
  r = r < lo ? lo : (r > hi ? hi : r);
  return *(const float4*)(xi + (size_t)r * W + c0);
}

__global__ __launch_bounds__(256, 4) void ssf_pipe2(const float* __restrict__ x,
                                                    float* __restrict__ out) {
  __shared__ float ring_all[4][8 * 256];  // depth-8 var ring per wave (8 KB)

  const int tid = threadIdx.x;
  const int lane = tid & 63;
  const int wv = tid >> 6;
  float* const ring = ring_all[wv];

  // XCD-chunked block swizzle (1024 blocks, 8 XCDs -> bijective).
  const int b = blockIdx.x;
  const int bs = (b & 7) * 128 + (b >> 3);
  const int sid = __builtin_amdgcn_readfirstlane(bs * 4 + wv);
  const int img = sid >> 3;                // 0..511
  const int y0 = (sid & 7) * STRIP;        // strip base output row

  const float* const xi = x + (size_t)img * (W * W);
  float* const oi = out + (size_t)img * (W * W);

  const int vymin = (y0 * 251) / 255;
  int vymax = ((y0 + STRIP - 1) * 251) / 255 + 1;
  if (vymax > 251) vymax = 251;
  const int hi = vymax + 4;  // last x row used (<= 255)

  const int c0 = lane * 4;

  // ---- Per-lane horizontal bilinear constants ----
  const int q0 = (int)floorf((float)c0 * SC);
  float wxv[4];
  bool selA[4], selB[4];
#pragma unroll
  for (int i = 0; i < 4; ++i) {
    float xs = (float)(c0 + i) * SC;
    float x0f = floorf(xs);
    int x0i = (int)x0f;
    wxv[i] = xs - x0f;
    selA[i] = (x0i - q0) == i;
    int x1i = x0i + 1;
    if (x1i > 251) x1i = 251;
    selB[i] = (x1i - q0) == (i + 1);
  }

  // ---- Preload register ring: rows y0-6..y0+3 (clamped to [vymin, hi]) ----
  // Invariant at start of iter u: Rk = row y0-6+k+u, xn = y0+u,
  // P1 = y0+u+1, P2 = y0+u+2, P3 = y0+u+3 (all clamped).
  float4 R0 = ldrow(xi, y0 - 6, vymin, hi, c0);
  float4 R1 = ldrow(xi, y0 - 5, vymin, hi, c0);
  float4 R2 = ldrow(xi, y0 - 4, vymin, hi, c0);
  float4 R3 = ldrow(xi, y0 - 3, vymin, hi, c0);
  float4 R4 = ldrow(xi, y0 - 2, vymin, hi, c0);
  float4 R5 = ldrow(xi, y0 - 1, vymin, hi, c0);
  float4 xn = ldrow(xi, y0 + 0, vymin, hi, c0);
  float4 P1 = ldrow(xi, y0 + 1, vymin, hi, c0);
  float4 P2 = ldrow(xi, y0 + 2, vymin, hi, c0);
  float4 P3 = ldrow(xi, y0 + 3, vymin, hi, c0);

  const int nsrc = (lane < 63) ? lane + 1 : 63;  // neighbor lane (63: junk)

  // ---- Exchange-pipeline state (sums for the NEXT var row) ----
  float sP[4] = {0.f, 0.f, 0.f, 0.f}, qP[4] = {0.f, 0.f, 0.f, 0.f};
  float nsP[4] = {0.f, 0.f, 0.f, 0.f}, nqP[4] = {0.f, 0.f, 0.f, 0.f};

#define COMPUTE_EXCH(Af, Bf, Cf, Df, Ef)                                     \
  {                                                                          \
    float a1[4] = {Af.x, Af.y, Af.z, Af.w};                                  \
    float a2[4] = {Bf.x, Bf.y, Bf.z, Bf.w};                                  \
    float a3[4] = {Cf.x, Cf.y, Cf.z, Cf.w};                                  \
    float a4[4] = {Df.x, Df.y, Df.z, Df.w};                                  \
    float a5[4] = {Ef.x, Ef.y, Ef.z, Ef.w};                                  \
    _Pragma("unroll") for (int i = 0; i < 4; ++i) {                          \
      sP[i] = ((a1[i] + a2[i]) + (a3[i] + a4[i])) + a5[i];                   \
      qP[i] = fmaf(a1[i], a1[i],                                             \
                   fmaf(a2[i], a2[i],                                        \
                        fmaf(a3[i], a3[i], fmaf(a4[i], a4[i],                \
                                                a5[i] * a5[i]))));           \
    }                                                                        \
    _Pragma("unroll") for (int i = 0; i < 4; ++i) {                          \
      nsP[i] = __shfl(sP[i], nsrc, 64);                                      \
      nqP[i] = __shfl(qP[i], nsrc, 64);                                      \
    }                                                                        \
  }

  // Prologue: y0 in {192, 224} has vymin == y0-4 (first var row eaten at u=0).
  if (vymin == y0 - 4) {
    COMPUTE_EXCH(R2, R3, R4, R5, xn);
  }

  int cur = -1000;
  float gl[5] = {0.f, 0.f, 0.f, 0.f, 0.f};  // gather: ring row vy  @ q0..q0+4
  float gh[5] = {0.f, 0.f, 0.f, 0.f, 0.f};  // gather: ring row vy1 @ q0..q0+4

  for (int u = 0; u <= 37; ++u) {  // fixed 38 iterations
    // ---- Issue next x-row load (3-iter slack before first use) ----
    float4 ldN = ldrow(xi, y0 + u + 4, vymin, hi, c0);

    // ---- Var row a: consume last iteration's sums + shfl results ----
    const int a = y0 - 4 + u;
    if (a >= vymin && a <= vymax) {
      float hs0 = ((sP[0] + sP[1]) + (sP[2] + sP[3])) + nsP[0];
      float hq0 = ((qP[0] + qP[1]) + (qP[2] + qP[3])) + nqP[0];
      float hs1 = hs0 - sP[0] + nsP[1];
      float hq1 = hq0 - qP[0] + nqP[1];
      float hs2 = hs1 - sP[1] + nsP[2];
      float hq2 = hq1 - qP[1] + nqP[2];
      float hs3 = hs2 - sP[2] + nsP[3];
      float hq3 = hq2 - qP[2] + nqP[3];
      float4 vr4;
      vr4.x = (hq0 - hs0 * hs0 * (1.0f / 25.0f)) * (1.0f / 24.0f);
      vr4.y = (hq1 - hs1 * hs1 * (1.0f / 25.0f)) * (1.0f / 24.0f);
      vr4.z = (hq2 - hs2 * hs2 * (1.0f / 25.0f)) * (1.0f / 24.0f);
      vr4.w = (hq3 - hs3 * hs3 * (1.0f / 25.0f)) * (1.0f / 24.0f);
      *(float4*)(ring + (a & 7) * 256 + c0) = vr4;
    }

    // ---- Compute next var row's sums + issue its shfls (1-iter slack) ----
    const int aN = a + 1;
    if (aN >= vymin && aN <= vymax) {
      COMPUTE_EXCH(R3, R4, R5, xn, P1);
    }

    // ---- Emit row gy = y0+u-6 from R0, gather prepared LAST iteration ----
    // (must run before gather-prep overwrites gl/gh — r9 bug)
    if (u >= 6) {
      const int gy = y0 + u - 6;
      const int vy = (gy * 251) / 255;  // exact integer floor (wave-uniform)
      float ys = (float)gy * SC;
      float wy = ys - (float)vy;
      float xa[4] = {R0.x, R0.y, R0.z, R0.w};
      float omwy = 1.0f - wy;
      float res[4];
#pragma unroll
      for (int i = 0; i < 4; ++i) {
        float a00 = (i == 0) ? gl[0] : (selA[i] ? gl[i] : gl[i - 1]);
        float a10 = (i == 0) ? gh[0] : (selA[i] ? gh[i] : gh[i - 1]);
        float a01 = selB[i] ? gl[i + 1] : gl[i];
        float a11 = selB[i] ? gh[i + 1] : gh[i];
        // Reference order: rows (wy) first, then cols (wx).
        float left = a00 * omwy + a10 * wy;
        float right = a01 * omwy + a11 * wy;
        res[i] = (left * (1.0f - wxv[i]) + right * wxv[i]) * xa[i];
      }
      *(float4*)(oi + (size_t)gy * W + c0) =
          make_float4(res[0], res[1], res[2], res[3]);
    }

    // ---- Gather-prep for next emit (gy' = y0+u-5); rows <= a are ready ----
    if (u >= 5 && u <= 36) {
      const int gyp = y0 + u - 5;
      const int vyp = (gyp * 251) / 255;
      int vy1p = vyp + 1;
      if (vy1p > 251) vy1p = 251;
      if (vyp != cur) {  // wave-uniform
        if (vyp == cur + 1) {
#pragma unroll
          for (int i = 0; i < 5; ++i) gl[i] = gh[i];  // row-carry reuse
        } else {
          const float* rp = ring + (vyp & 7) * 256 + q0;  // first emit only
#pragma unroll
          for (int i = 0; i < 5; ++i) gl[i] = rp[i];
        }
        if (vy1p == vyp) {
#pragma unroll
          for (int i = 0; i < 5; ++i) gh[i] = gl[i];  // bottom clamp
        } else {
          const float* rp = ring + (vy1p & 7) * 256 + q0;
#pragma unroll
          for (int i = 0; i < 5; ++i) gh[i] = rp[i];
        }
        cur = vyp;
      }
    }

    // ---- Static ring shift (named registers, no dynamic indexing) ----
    R0 = R1; R1 = R2; R2 = R3; R3 = R4; R4 = R5; R5 = xn;
    xn = P1; P1 = P2; P2 = P3; P3 = ldN;
  }
#undef COMPUTE_EXCH
}

}  // namespace

extern "C" void kernel_launch(void* const* d_in, const int* in_sizes, int n_in,
                              void* d_out, int out_size, void* d_ws, size_t ws_size,
                              hipStream_t stream) {
  const float* x = (const float*)d_in[0];
  float* out = (float*)d_out;
  // 4096 strips (512 images x 8 strips), 4 waves (strips) per 256-thread block.
  ssf_pipe2<<<dim3(1024), dim3(256), 0, stream>>>(x, out);
}

// Round 12
// 48.247 us; speedup vs baseline: 1.0334x; 1.0239x over previous
//
#include <hip/hip_runtime.h>

// SSF_Extractor: out = x * resize_bilinear_ac(local_unbiased_var_5x5(x), 256, 256)
// x: (8, 64, 256, 256) fp32.
//
// r10 structure + NON-TEMPORAL output stores: output is write-once data;
// letting it allocate in L2/L3 evicts x (128 MB, otherwise fully L3-resident)
// and makes HBM serve mixed read+write. nt stores keep x cached -> HBM
// becomes a near-pure write stream. (r11 fix: __builtin_nontemporal_store
// needs a clang native vector type, not HIP's float4 class.)
//
// Fully-pipelined single-load streaming: one 64-lane wave owns one
// 32-output-row full-width strip; lane l owns columns 4l..4l+3. A 10-deep
// named-register ring (R0..R5, xn, P1..P3) holds the last 10 x-rows; each x
// byte is loaded from global exactly once per wave. Neighbor column-sum
// exchange (8 x __shfl) issued one iteration ahead of consumption.
// ORDER: emit consumes gl/gh BEFORE gather-prep overwrites them (r9 bug).

namespace {

constexpr int W = 256;
constexpr int STRIP = 32;
#define SC (251.0f / 255.0f)  // align_corners scale (h-1)/(H-1)

typedef float vfloat4 __attribute__((ext_vector_type(4)));

__device__ __forceinline__ float4 ldrow(const float* xi, int r, int lo, int hi,
                                        int c0) {
  r = r < lo ? lo : (r > hi ? hi : r);
  return *(const float4*)(xi + (size_t)r * W + c0);
}

__global__ __launch_bounds__(256, 4) void ssf_pipe3(const float* __restrict__ x,
                                                    float* __restrict__ out) {
  __shared__ float ring_all[4][8 * 256];  // depth-8 var ring per wave (8 KB)

  const int tid = threadIdx.x;
  const int lane = tid & 63;
  const int wv = tid >> 6;
  float* const ring = ring_all[wv];

  // XCD-chunked block swizzle (1024 blocks, 8 XCDs -> bijective).
  const int b = blockIdx.x;
  const int bs = (b & 7) * 128 + (b >> 3);
  const int sid = __builtin_amdgcn_readfirstlane(bs * 4 + wv);
  const int img = sid >> 3;                // 0..511
  const int y0 = (sid & 7) * STRIP;        // strip base output row

  const float* const xi = x + (size_t)img * (W * W);
  float* const oi = out + (size_t)img * (W * W);

  const int vymin = (y0 * 251) / 255;
  int vymax = ((y0 + STRIP - 1) * 251) / 255 + 1;
  if (vymax > 251) vymax = 251;
  const int hi = vymax + 4;  // last x row used (<= 255)

  const int c0 = lane * 4;

  // ---- Per-lane horizontal bilinear constants ----
  const int q0 = (int)floorf((float)c0 * SC);
  float wxv[4];
  bool selA[4], selB[4];
#pragma unroll
  for (int i = 0; i < 4; ++i) {
    float xs = (float)(c0 + i) * SC;
    float x0f = floorf(xs);
    int x0i = (int)x0f;
    wxv[i] = xs - x0f;
    selA[i] = (x0i - q0) == i;
    int x1i = x0i + 1;
    if (x1i > 251) x1i = 251;
    selB[i] = (x1i - q0) == (i + 1);
  }

  // ---- Preload register ring: rows y0-6..y0+3 (clamped to [vymin, hi]) ----
  // Invariant at start of iter u: Rk = row y0-6+k+u, xn = y0+u,
  // P1 = y0+u+1, P2 = y0+u+2, P3 = y0+u+3 (all clamped).
  float4 R0 = ldrow(xi, y0 - 6, vymin, hi, c0);
  float4 R1 = ldrow(xi, y0 - 5, vymin, hi, c0);
  float4 R2 = ldrow(xi, y0 - 4, vymin, hi, c0);
  float4 R3 = ldrow(xi, y0 - 3, vymin, hi, c0);
  float4 R4 = ldrow(xi, y0 - 2, vymin, hi, c0);
  float4 R5 = ldrow(xi, y0 - 1, vymin, hi, c0);
  float4 xn = ldrow(xi, y0 + 0, vymin, hi, c0);
  float4 P1 = ldrow(xi, y0 + 1, vymin, hi, c0);
  float4 P2 = ldrow(xi, y0 + 2, vymin, hi, c0);
  float4 P3 = ldrow(xi, y0 + 3, vymin, hi, c0);

  const int nsrc = (lane < 63) ? lane + 1 : 63;  // neighbor lane (63: junk)

  // ---- Exchange-pipeline state (sums for the NEXT var row) ----
  float sP[4] = {0.f, 0.f, 0.f, 0.f}, qP[4] = {0.f, 0.f, 0.f, 0.f};
  float nsP[4] = {0.f, 0.f, 0.f, 0.f}, nqP[4] = {0.f, 0.f, 0.f, 0.f};

#define COMPUTE_EXCH(Af, Bf, Cf, Df, Ef)                                     \
  {                                                                          \
    float a1[4] = {Af.x, Af.y, Af.z, Af.w};                                  \
    float a2[4] = {Bf.x, Bf.y, Bf.z, Bf.w};                                  \
    float a3[4] = {Cf.x, Cf.y, Cf.z, Cf.w};                                  \
    float a4[4] = {Df.x, Df.y, Df.z, Df.w};                                  \
    float a5[4] = {Ef.x, Ef.y, Ef.z, Ef.w};                                  \
    _Pragma("unroll") for (int i = 0; i < 4; ++i) {                          \
      sP[i] = ((a1[i] + a2[i]) + (a3[i] + a4[i])) + a5[i];                   \
      qP[i] = fmaf(a1[i], a1[i],                                             \
                   fmaf(a2[i], a2[i],                                        \
                        fmaf(a3[i], a3[i], fmaf(a4[i], a4[i],                \
                                                a5[i] * a5[i]))));           \
    }                                                                        \
    _Pragma("unroll") for (int i = 0; i < 4; ++i) {                          \
      nsP[i] = __shfl(sP[i], nsrc, 64);                                      \
      nqP[i] = __shfl(qP[i], nsrc, 64);                                      \
    }                                                                        \
  }

  // Prologue: y0 in {192, 224} has vymin == y0-4 (first var row eaten at u=0).
  if (vymin == y0 - 4) {
    COMPUTE_EXCH(R2, R3, R4, R5, xn);
  }

  int cur = -1000;
  float gl[5] = {0.f, 0.f, 0.f, 0.f, 0.f};  // gather: ring row vy  @ q0..q0+4
  float gh[5] = {0.f, 0.f, 0.f, 0.f, 0.f};  // gather: ring row vy1 @ q0..q0+4

  for (int u = 0; u <= 37; ++u) {  // fixed 38 iterations
    // ---- Issue next x-row load (3-iter slack before first use) ----
    float4 ldN = ldrow(xi, y0 + u + 4, vymin, hi, c0);

    // ---- Var row a: consume last iteration's sums + shfl results ----
    const int a = y0 - 4 + u;
    if (a >= vymin && a <= vymax) {
      float hs0 = ((sP[0] + sP[1]) + (sP[2] + sP[3])) + nsP[0];
      float hq0 = ((qP[0] + qP[1]) + (qP[2] + qP[3])) + nqP[0];
      float hs1 = hs0 - sP[0] + nsP[1];
      float hq1 = hq0 - qP[0] + nqP[1];
      float hs2 = hs1 - sP[1] + nsP[2];
      float hq2 = hq1 - qP[1] + nqP[2];
      float hs3 = hs2 - sP[2] + nsP[3];
      float hq3 = hq2 - qP[2] + nqP[3];
      float4 vr4;
      vr4.x = (hq0 - hs0 * hs0 * (1.0f / 25.0f)) * (1.0f / 24.0f);
      vr4.y = (hq1 - hs1 * hs1 * (1.0f / 25.0f)) * (1.0f / 24.0f);
      vr4.z = (hq2 - hs2 * hs2 * (1.0f / 25.0f)) * (1.0f / 24.0f);
      vr4.w = (hq3 - hs3 * hs3 * (1.0f / 25.0f)) * (1.0f / 24.0f);
      *(float4*)(ring + (a & 7) * 256 + c0) = vr4;
    }

    // ---- Compute next var row's sums + issue its shfls (1-iter slack) ----
    const int aN = a + 1;
    if (aN >= vymin && aN <= vymax) {
      COMPUTE_EXCH(R3, R4, R5, xn, P1);
    }

    // ---- Emit row gy = y0+u-6 from R0, gather prepared LAST iteration ----
    // (must run before gather-prep overwrites gl/gh)
    if (u >= 6) {
      const int gy = y0 + u - 6;
      const int vy = (gy * 251) / 255;  // exact integer floor (wave-uniform)
      float ys = (float)gy * SC;
      float wy = ys - (float)vy;
      float xa[4] = {R0.x, R0.y, R0.z, R0.w};
      float omwy = 1.0f - wy;
      float res[4];
#pragma unroll
      for (int i = 0; i < 4; ++i) {
        float a00 = (i == 0) ? gl[0] : (selA[i] ? gl[i] : gl[i - 1]);
        float a10 = (i == 0) ? gh[0] : (selA[i] ? gh[i] : gh[i - 1]);
        float a01 = selB[i] ? gl[i + 1] : gl[i];
        float a11 = selB[i] ? gh[i + 1] : gh[i];
        // Reference order: rows (wy) first, then cols (wx).
        float left = a00 * omwy + a10 * wy;
        float right = a01 * omwy + a11 * wy;
        res[i] = (left * (1.0f - wxv[i]) + right * wxv[i]) * xa[i];
      }
      // Non-temporal: output is write-once; don't evict x from L2/L3.
      vfloat4 rv = {res[0], res[1], res[2], res[3]};
      __builtin_nontemporal_store(rv, (vfloat4*)(oi + (size_t)gy * W + c0));
    }

    // ---- Gather-prep for next emit (gy' = y0+u-5); rows <= a are ready ----
    if (u >= 5 && u <= 36) {
      const int gyp = y0 + u - 5;
      const int vyp = (gyp * 251) / 255;
      int vy1p = vyp + 1;
      if (vy1p > 251) vy1p = 251;
      if (vyp != cur) {  // wave-uniform
        if (vyp == cur + 1) {
#pragma unroll
          for (int i = 0; i < 5; ++i) gl[i] = gh[i];  // row-carry reuse
        } else {
          const float* rp = ring + (vyp & 7) * 256 + q0;  // first emit only
#pragma unroll
          for (int i = 0; i < 5; ++i) gl[i] = rp[i];
        }
        if (vy1p == vyp) {
#pragma unroll
          for (int i = 0; i < 5; ++i) gh[i] = gl[i];  // bottom clamp
        } else {
          const float* rp = ring + (vy1p & 7) * 256 + q0;
#pragma unroll
          for (int i = 0; i < 5; ++i) gh[i] = rp[i];
        }
        cur = vyp;
      }
    }

    // ---- Static ring shift (named registers, no dynamic indexing) ----
    R0 = R1; R1 = R2; R2 = R3; R3 = R4; R4 = R5; R5 = xn;
    xn = P1; P1 = P2; P2 = P3; P3 = ldN;
  }
#undef COMPUTE_EXCH
}

}  // namespace

extern "C" void kernel_launch(void* const* d_in, const int* in_sizes, int n_in,
                              void* d_out, int out_size, void* d_ws, size_t ws_size,
                              hipStream_t stream) {
  const float* x = (const float*)d_in[0];
  float* out = (float*)d_out;
  // 4096 strips (512 images x 8 strips), 4 waves (strips) per 256-thread block.
  ssf_pipe3<<<dim3(1024), dim3(256), 0, stream>>>(x, out);
}